// Round 2
// baseline (1771.766 us; speedup 1.0000x reference)
//
#include <hip/hip_runtime.h>
#include <math.h>

#define BB 2
#define HH 16
#define SS 2048
#define DD 64
#define TQ 8          // q rows per block; LDS ~72 KiB => 2 blocks/CU
#define FSTRIDE 2052  // f32 score row stride: %4==0 for b128, %32==4 breaks bank conflicts
#define ERS 2056      // e-plane row stride in shorts: row r starts at bank 4r (mod 32)
#define ELO (8 * ERS) // lo-plane offset (shorts)

typedef __attribute__((ext_vector_type(8))) short bf16x8;
typedef __attribute__((ext_vector_type(4))) float f32x4;
typedef __attribute__((ext_vector_type(4))) int i32x4;
typedef __attribute__((ext_vector_type(4))) unsigned short u16x4;

__device__ __forceinline__ unsigned short f2bf(float f) {
    unsigned u = __float_as_uint(f);
    u += 0x7FFF + ((u >> 16) & 1);   // RNE
    return (unsigned short)(u >> 16);
}
__device__ __forceinline__ float bf2f(unsigned short h) {
    return __uint_as_float(((unsigned)h) << 16);
}

// Exact integer-threshold T5 bucket (bidirectional, 32 buckets, max_distance=128).
__device__ __forceinline__ int rel_bucket(int cpq, int mpk) {
    int n = cpq - mpk;            // n = -(mem - ctx)
    int ret = 0;
    if (n < 0) { ret = 16; n = -n; }
    int v;
    if (n < 8) v = n;
    else {
        int j = (n >= 12) + (n >= 16) + (n >= 23) + (n >= 32) +
                (n >= 46) + (n >= 64) + (n >= 91);
        v = 8 + j;
    }
    return ret + v;
}

// Pre-kernel 1: K f32 -> bf16 once (8.4 MiB into d_ws).
__launch_bounds__(256)
__global__ void conv_k_bf16(const float* __restrict__ src,
                            unsigned short* __restrict__ dst) {
    const size_t i = ((size_t)blockIdx.x * 256 + threadIdx.x) * 8;
    float4 f0 = *(const float4*)(src + i);
    float4 f1 = *(const float4*)(src + i + 4);
    union { bf16x8 v; unsigned short u[8]; } o;
    o.u[0] = f2bf(f0.x); o.u[1] = f2bf(f0.y); o.u[2] = f2bf(f0.z); o.u[3] = f2bf(f0.w);
    o.u[4] = f2bf(f1.x); o.u[5] = f2bf(f1.y); o.u[6] = f2bf(f1.z); o.u[7] = f2bf(f1.w);
    *(bf16x8*)(dst + i) = o.v;
}

// Pre-kernel 2: V -> transposed split-bf16 planes vt_hi/vt_lo [bh][d][c].
// Makes PV B-fragments a single contiguous b128 load per plane.
__launch_bounds__(256)
__global__ void conv_v_t(const float* __restrict__ v,
                         unsigned short* __restrict__ vt_hi,
                         unsigned short* __restrict__ vt_lo) {
    __shared__ float tile[64][65];
    const int bh = blockIdx.x >> 5;
    const int ct = blockIdx.x & 31;
    const int c0 = ct * 64;
    const float* vb = v + ((size_t)bh * SS + c0) * DD;
    const int tid = threadIdx.x;
    #pragma unroll
    for (int it = 0; it < 16; ++it) {
        const int idx = it * 256 + tid;
        tile[idx >> 6][idx & 63] = vb[idx];           // coalesced read
    }
    __syncthreads();
    #pragma unroll
    for (int it = 0; it < 16; ++it) {
        const int idx = it * 256 + tid;
        const int d = idx >> 6, c = idx & 63;
        const float val = tile[c][d];                  // stride-65: conflict-free
        const unsigned short hi = f2bf(val);
        const unsigned short lo = f2bf(val - bf2f(hi));
        const size_t o = ((size_t)bh * DD + d) * SS + c0 + c;  // coalesced write
        vt_hi[o] = hi;
        vt_lo[o] = lo;
    }
}

__launch_bounds__(512, 4)   // 2 blocks/CU of 512 threads
__global__ void attn_tile_kernel(const float* __restrict__ qg,
                                 const unsigned short* __restrict__ kb,
                                 const unsigned short* __restrict__ vt_hi,
                                 const unsigned short* __restrict__ vt_lo,
                                 const float* __restrict__ bw,
                                 const int*   __restrict__ cp,
                                 const int*   __restrict__ mp,
                                 const int*   __restrict__ mask,
                                 float* __restrict__ o_out,
                                 float* __restrict__ a_out,
                                 float* __restrict__ p_out) {
    // strip_sh aliases: f32 scores [8][FSTRIDE] (phase A->B1), then planar
    // bf16 e-planes ehi[8][ERS] + elo[8][ERS] (phase B2->E). 65792 B.
    __shared__ __align__(16) unsigned short strip_sh[2 * 8 * ERS];
    __shared__ __align__(16) float partials[2 * TQ * DD];     // 4 KiB (2 K-halves)
    __shared__ __align__(16) unsigned short q_lds[16 * 72];   // 2304 B
    __shared__ float bwh[32];
    __shared__ float invl[TQ];
    float* strip = (float*)strip_sh;
    // total ~72.3 KiB => 2 blocks/CU

    const int tid = threadIdx.x;
    // XCD-aware swizzle: 4 heads per XCD share K/V in L2; the 4 heads of one
    // q-tile run concurrently (mask rows shared across heads).
    const int x   = blockIdx.x;
    const int xcd = x & 7;
    const int s_  = x >> 3;
    const int bh  = xcd * 4 + (s_ & 3);
    const int qt  = s_ >> 2;
    const int b   = bh >> 4;
    const int h   = bh & 15;
    const int q0  = qt * TQ;

    const unsigned short* Kbase = kb + (size_t)bh * SS * DD;

    // ---- stage Q tile (bf16, pre-scaled by 1/8 == exact pow2) + bias column ----
    {
        const float* Qrow = qg + ((size_t)bh * SS + q0) * DD;
        for (int e = tid; e < 16 * DD; e += 512) {
            int r = e >> 6, d = e & 63;
            q_lds[r * 72 + d] = (r < TQ) ? f2bf(Qrow[r * DD + d] * 0.125f)
                                         : (unsigned short)0;
        }
        if (tid < 32) bwh[tid] = bw[tid * HH + h];
    }
    __syncthreads();

    const int lane = tid & 63;
    const int wave = tid >> 6;
    const int quad = lane >> 4;
    const int l16  = lane & 15;

    // ---- Phase A: QK^T via MFMA 16x16x32 bf16 -> f32 strip (scaled scores) ----
    {
        bf16x8 a0 = *(const bf16x8*)&q_lds[l16 * 72 + quad * 8];        // dims 0..31
        bf16x8 a1 = *(const bf16x8*)&q_lds[l16 * 72 + 32 + quad * 8];   // dims 32..63
        for (int ii = 0; ii < 16; ++ii) {
            const int kt = wave * 16 + ii;
            const unsigned short* kp = Kbase + (size_t)(kt * 16 + l16) * DD + quad * 8;
            bf16x8 b0 = *(const bf16x8*)(kp);
            bf16x8 b1 = *(const bf16x8*)(kp + 32);
            f32x4 acc = {0.f, 0.f, 0.f, 0.f};
            acc = __builtin_amdgcn_mfma_f32_16x16x32_bf16(a0, b0, acc, 0, 0, 0);
            acc = __builtin_amdgcn_mfma_f32_16x16x32_bf16(a1, b1, acc, 0, 0, 0);
            // C: row=(lane>>4)*4+reg, col=lane&15; rows >= TQ discarded
            if (quad < 2) {
                const int col = kt * 16 + l16;
                const int rb  = quad * 4;
                strip[(rb + 0) * FSTRIDE + col] = acc[0];
                strip[(rb + 1) * FSTRIDE + col] = acc[1];
                strip[(rb + 2) * FSTRIDE + col] = acc[2];
                strip[(rb + 3) * FSTRIDE + col] = acc[3];
            }
        }
    }
    __syncthreads();

    // ---- Phase B1: one wave per q-row. Read s -> regs, bias+mask, p_out, max ----
    // ---- Phase B2: e=exp, sum, a_out from regs, write planar bf16 e-planes  ----
    {
        const int r  = wave;
        const int i  = lane;
        const int qi = q0 + r;
        const int cpq = cp[b * SS + qi];
        const int* mrow = mask + ((size_t)b * SS + qi) * SS;
        const int* mpb  = mp + b * SS;
        float* prow = p_out + ((size_t)bh * SS + qi) * SS;
        const float* srow = strip + r * FSTRIDE;
        float sv[32];
        float mx = -3.0e38f;
        #pragma unroll
        for (int j = 0; j < 8; ++j) {
            const int c0 = (i + 64 * j) * 4;           // 16 B/lane, coalesced
            i32x4 m4  = *(const i32x4*)(mrow + c0);
            i32x4 mp4 = *(const i32x4*)(mpb + c0);
            f32x4 s4  = *(const f32x4*)(srow + c0);
            f32x4 p4;
            #pragma unroll
            for (int u = 0; u < 4; ++u) {
                p4[u] = bwh[rel_bucket(cpq, mp4[u])];
                float s = s4[u] + p4[u];
                if (m4[u] != 0) s = -1.0e9f;
                sv[j * 4 + u] = s;
                mx = fmaxf(mx, s);
            }
            *(f32x4*)(prow + c0) = p4;
        }
        #pragma unroll
        for (int off = 32; off >= 1; off >>= 1)
            mx = fmaxf(mx, __shfl_xor(mx, off));

        __syncthreads();   // all f32 strip reads done before bf16 overwrite

        float sum = 0.f;
        #pragma unroll
        for (int j = 0; j < 32; ++j) {
            sv[j] = __expf(sv[j] - mx);
            sum += sv[j];
        }
        #pragma unroll
        for (int off = 32; off >= 1; off >>= 1)
            sum += __shfl_xor(sum, off);
        const float inv = 1.0f / sum;
        if (i == 0) invl[r] = inv;

        unsigned short* ehr = strip_sh + r * ERS;
        unsigned short* elr = strip_sh + ELO + r * ERS;
        float* arow = a_out + ((size_t)bh * SS + qi) * SS;
        #pragma unroll
        for (int j = 0; j < 8; ++j) {
            const int c0 = (i + 64 * j) * 4;
            f32x4 o4;
            u16x4 h4, l4;
            #pragma unroll
            for (int u = 0; u < 4; ++u) {
                const float e = sv[j * 4 + u];
                o4[u] = e * inv;
                const unsigned short hi = f2bf(e);
                h4[u] = hi;
                l4[u] = f2bf(e - bf2f(hi));
            }
            *(f32x4*)(arow + c0) = o4;     // fused phase D: attn out from regs
            *(u16x4*)(ehr + c0) = h4;      // planar hi plane (b64)
            *(u16x4*)(elr + c0) = l4;      // planar lo plane (b64)
        }
    }
    __syncthreads();

    // ---- Phase E: PV via split-bf16 MFMA. wave -> (K-half, d-tile of 16) ----
    // o[r][d] = sum_c e[r][c] * v[c][d], e ~= ehi+elo, v ~= vhi+vlo.
    // 3 MFMAs/step (hh, lh, hl); lo*lo term ~2^-18, dropped.
    // A rows 8..15 are duplicates of 0..7 -> garbage only in discarded C rows.
    {
        const int kc = wave >> 2;            // K half: 0..1
        const int d0 = (wave & 3) * 16;      // d tile
        const unsigned short* vhiB = vt_hi + ((size_t)bh * DD + d0 + l16) * SS;
        const unsigned short* vloB = vt_lo + ((size_t)bh * DD + d0 + l16) * SS;
        const unsigned short* ehB = strip_sh + (l16 & 7) * ERS + quad * 8;
        const unsigned short* elB = strip_sh + ELO + (l16 & 7) * ERS + quad * 8;
        f32x4 acc1 = {0.f, 0.f, 0.f, 0.f};   // hi*hi
        f32x4 acc2 = {0.f, 0.f, 0.f, 0.f};   // lo*hi
        f32x4 acc3 = {0.f, 0.f, 0.f, 0.f};   // hi*lo
        #pragma unroll 4
        for (int s = 0; s < 32; ++s) {
            const int k0 = kc * 1024 + s * 32;
            bf16x8 ahi = *(const bf16x8*)(ehB + k0);            // per-lane LDS b128
            bf16x8 alo = *(const bf16x8*)(elB + k0);
            bf16x8 bhi = *(const bf16x8*)(vhiB + k0 + quad * 8); // contiguous global b128
            bf16x8 blo = *(const bf16x8*)(vloB + k0 + quad * 8);
            acc1 = __builtin_amdgcn_mfma_f32_16x16x32_bf16(ahi, bhi, acc1, 0, 0, 0);
            acc2 = __builtin_amdgcn_mfma_f32_16x16x32_bf16(alo, bhi, acc2, 0, 0, 0);
            acc3 = __builtin_amdgcn_mfma_f32_16x16x32_bf16(ahi, blo, acc3, 0, 0, 0);
        }
        if (quad < 2) {                       // keep C rows 0..7 only
            #pragma unroll
            for (int rg = 0; rg < 4; ++rg) {
                const int row = quad * 4 + rg;
                partials[kc * (TQ * DD) + row * DD + d0 + l16] =
                    acc1[rg] + acc2[rg] + acc3[rg];
            }
        }
    }
    __syncthreads();

    // ---- reduce over 2 K-halves, apply 1/l, write out ----
    {
        const int r = tid >> 6;               // 512 threads = TQ*DD elems
        const float v = partials[tid] + partials[512 + tid];
        o_out[((size_t)bh * SS + q0 + r) * DD + (tid & 63)] = v * invl[r];
    }
}

extern "C" void kernel_launch(void* const* d_in, const int* in_sizes, int n_in,
                              void* d_out, int out_size, void* d_ws, size_t ws_size,
                              hipStream_t stream) {
    const float* q  = (const float*)d_in[0];
    const float* k  = (const float*)d_in[1];
    const float* v  = (const float*)d_in[2];
    const float* bw = (const float*)d_in[3];
    const int*   cp = (const int*)d_in[4];
    const int*   mp = (const int*)d_in[5];
    const int*   mask = (const int*)d_in[6];

    float* o_out = (float*)d_out;                                   // [B,H,S,D]
    float* a_out = o_out + (size_t)BB * HH * SS * DD;               // [B,H,S,S]
    float* p_out = a_out + (size_t)BB * HH * SS * SS;               // [B,H,S,S]

    // workspace: K bf16 (8.4 MB) + V^T hi plane (8.4 MB) + V^T lo plane (8.4 MB)
    const size_t NE = (size_t)BB * HH * SS * DD;     // 4,194,304 elements
    unsigned short* kb    = (unsigned short*)d_ws;
    unsigned short* vt_hi = kb + NE;
    unsigned short* vt_lo = kb + 2 * NE;

    const int conv_grid = (int)(NE / (8 * 256));     // 2048 blocks, exact
    conv_k_bf16<<<conv_grid, 256, 0, stream>>>(k, kb);
    conv_v_t<<<BB * HH * (SS / 64), 256, 0, stream>>>(v, vt_hi, vt_lo);

    const int grid = BB * HH * (SS / TQ);            // 8192 blocks
    attn_tile_kernel<<<grid, 512, 0, stream>>>(q, kb, vt_hi, vt_lo, bw, cp, mp, mask,
                                               o_out, a_out, p_out);
}